// Round 6
// baseline (152.257 us; speedup 1.0000x reference)
//
#include <hip/hip_runtime.h>
#include <hip/hip_bf16.h>

#define S 4096
#define DMODEL 1024
#define DK 128
#define NB_ATTN 2112   // sum over 32-row tiles t of ceil((t+1)/4), chunk=128

typedef __attribute__((ext_vector_type(8))) short  short8;   // 8 x bf16 (4 VGPRs)
typedef __attribute__((ext_vector_type(4))) float  f32x4;    // MFMA accumulator
typedef __attribute__((ext_vector_type(4))) unsigned short u16x4;  // 8B pack

__device__ __forceinline__ unsigned short f2bf(float f) {
    return __builtin_bit_cast(unsigned short, __float2bfloat16(f));
}

__device__ __forceinline__ short8 cvt8(float4 a, float4 b) {
    short8 v;
    v[0] = (short)f2bf(a.x); v[1] = (short)f2bf(a.y);
    v[2] = (short)f2bf(a.z); v[3] = (short)f2bf(a.w);
    v[4] = (short)f2bf(b.x); v[5] = (short)f2bf(b.y);
    v[6] = (short)f2bf(b.z); v[7] = (short)f2bf(b.w);
    return v;
}

// ---------------------------------------------------------------------------
// Convert X [S][DMODEL] f32 -> Xb bf16; Wq|Wk|Wv [DK][DMODEL] f32 -> Wb bf16.
// ---------------------------------------------------------------------------
__global__ __launch_bounds__(256) void cvt_kernel(
    const float* __restrict__ X,
    const float* __restrict__ Wq, const float* __restrict__ Wk,
    const float* __restrict__ Wv,
    unsigned short* __restrict__ Xb, unsigned short* __restrict__ Wb)
{
    const int i = blockIdx.x * 256 + threadIdx.x;
    const float* __restrict__ src;
    unsigned short* __restrict__ dst;
    size_t off;
    if (i < 524288) {
        src = X; dst = Xb; off = (size_t)i * 8;
    } else {
        const int j   = i - 524288;
        const int sel = j >> 14, jj = j & 16383;
        src = sel == 0 ? Wq : sel == 1 ? Wk : Wv;
        dst = Wb + (size_t)sel * DK * DMODEL;
        off = (size_t)jj * 8;
    }
    const float4 a = *(const float4*)(src + off);
    const float4 b = *(const float4*)(src + off + 4);
    *(short8*)(dst + off) = cvt8(a, b);
}

// ---------------------------------------------------------------------------
// QKV projection GEMM, bf16. grid = (S/16, 3), block = 128 (2 waves).
// Wave w: 16 rows x 64 cols. sel==2 (V) writes DIRECTLY TRANSPOSED to
// Vt[DK][S] via packed 8B stores (acc regs r are 4 consecutive s-rows).
// ---------------------------------------------------------------------------
__global__ __launch_bounds__(128) void proj_gemm(
    const unsigned short* __restrict__ Xb, const unsigned short* __restrict__ Wb,
    const float* __restrict__ bq, const float* __restrict__ bk,
    const float* __restrict__ bv,
    unsigned short* __restrict__ Qb, unsigned short* __restrict__ Kb,
    unsigned short* __restrict__ Vt)
{
    const int sel = blockIdx.y;
    const float* __restrict__ bias = sel == 0 ? bq : sel == 1 ? bk : bv;
    const unsigned short* __restrict__ wbase = Wb + (size_t)sel * DK * DMODEL;

    const int tid = threadIdx.x, w = tid >> 6, lane = tid & 63;
    const int li = lane & 15, gl = lane >> 4;
    const int r0 = blockIdx.x * 16;
    const int n0 = w * 64;

    f32x4 acc[4];
    #pragma unroll
    for (int j = 0; j < 4; ++j)
        #pragma unroll
        for (int r = 0; r < 4; ++r) acc[j][r] = 0.f;

    const unsigned short* ap  = &Xb[(size_t)(r0 + li) * DMODEL + 8 * gl];
    const unsigned short* bp0 = &wbase[(size_t)(n0 + li) * DMODEL + 8 * gl];
    const unsigned short* bp1 = bp0 + (size_t)16 * DMODEL;
    const unsigned short* bp2 = bp0 + (size_t)32 * DMODEL;
    const unsigned short* bp3 = bp0 + (size_t)48 * DMODEL;

    #pragma unroll 4
    for (int k0 = 0; k0 < DMODEL; k0 += 32) {
        const short8 a  = *(const short8*)(ap + k0);
        const short8 b0 = *(const short8*)(bp0 + k0);
        const short8 b1 = *(const short8*)(bp1 + k0);
        const short8 b2 = *(const short8*)(bp2 + k0);
        const short8 b3 = *(const short8*)(bp3 + k0);
        acc[0] = __builtin_amdgcn_mfma_f32_16x16x32_bf16(a, b0, acc[0], 0, 0, 0);
        acc[1] = __builtin_amdgcn_mfma_f32_16x16x32_bf16(a, b1, acc[1], 0, 0, 0);
        acc[2] = __builtin_amdgcn_mfma_f32_16x16x32_bf16(a, b2, acc[2], 0, 0, 0);
        acc[3] = __builtin_amdgcn_mfma_f32_16x16x32_bf16(a, b3, acc[3], 0, 0, 0);
    }

    if (sel < 2) {
        unsigned short* __restrict__ Out = sel == 0 ? Qb : Kb;
        #pragma unroll
        for (int j = 0; j < 4; ++j)
            #pragma unroll
            for (int r = 0; r < 4; ++r) {
                const int row = r0 + 4 * gl + r;
                const int col = n0 + 16 * j + li;
                Out[(size_t)row * DK + col] = f2bf(acc[j][r] + bias[col]);
            }
    } else {
        #pragma unroll
        for (int j = 0; j < 4; ++j) {
            const int col = n0 + 16 * j + li;          // dv
            const float bb = bias[col];
            u16x4 wv;
            #pragma unroll
            for (int r = 0; r < 4; ++r) wv[r] = f2bf(acc[j][r] + bb);
            *(u16x4*)&Vt[(size_t)col * S + r0 + 4 * gl] = wv;  // rows 4gl..4gl+3
        }
    }
}

// ---------------------------------------------------------------------------
// Flash attention, bf16 MFMA, SWAPPED QK^T. 1 wave/block, 32 q-rows/wave,
// chunk = 128 keys. Tile group j = ceil((t+1)/4): tiles 4(j-1)..4j-1 each
// have j chunks; block base 2j(j-1). 2112 blocks, heavy-first dispatch.
//
// QK: D = mfma(K_frag, Q_frag) = S^T -> lane holds 8 scores (kt x r) for
// q = 32t+16qs+li; key = kb+16kt+4gl+r. Row max/sum: in-lane + shfl 16,32.
// (m,l) per-lane scalars. P packed to LDS (b64), reread as A-frag for PV
// (accv D-layout rows q=4gl+r -> corr broadcast via 4 shfls, rare branch).
// No __syncthreads needed: single-wave block, lgkmcnt orders Pl w->r.
// ---------------------------------------------------------------------------
__global__ __launch_bounds__(64) void attn_mfma(
    const unsigned short* __restrict__ Qb,
    const unsigned short* __restrict__ Kb,
    const unsigned short* __restrict__ Vt,
    float* __restrict__ OP, float* __restrict__ ML)
{
    const int b = (NB_ATTN - 1) - (int)blockIdx.x;   // heavy blocks first
    int j = 1;
    while (2 * (j + 1) * j <= b) ++j;                // <=31 scalar iters
    const int off = b - 2 * j * (j - 1);
    const int t   = 4 * (j - 1) + off / j;
    const int c   = off % j;
    const int kstart = 128 * c;
    const int kend   = min(128 * (c + 1), 32 * t + 32);

    const int lane = threadIdx.x, li = lane & 15, gl = lane >> 4;

    __shared__ unsigned short Pl[32][40];   // 80B rows; b64 writes, b128 reads

    short8 aq[2][4];
    #pragma unroll
    for (int qs = 0; qs < 2; ++qs)
        #pragma unroll
        for (int s = 0; s < 4; ++s)
            aq[qs][s] = *(const short8*)
                &Qb[(size_t)(32 * t + 16 * qs + li) * DK + 32 * s + 8 * gl];

    f32x4 accv[2][8];
    #pragma unroll
    for (int qs = 0; qs < 2; ++qs)
        #pragma unroll
        for (int n = 0; n < 8; ++n)
            #pragma unroll
            for (int r = 0; r < 4; ++r) accv[qs][n][r] = 0.f;

    float mr[2] = {-1e30f, -1e30f}, lr[2] = {0.f, 0.f};
    const float scale = 0.08838834764831845f;  // 1/sqrt(128)

    // ---- K register double-buffer: preload first tile (A-frag: row li)
    short8 bkc[2][4], bkn[2][4];
    #pragma unroll
    for (int kt = 0; kt < 2; ++kt)
        #pragma unroll
        for (int s = 0; s < 4; ++s)
            bkc[kt][s] = *(const short8*)
                &Kb[(size_t)(kstart + 16 * kt + li) * DK + 32 * s + 8 * gl];

    for (int kb = kstart; kb < kend; kb += 32) {
        // ---- V loads for this iter (consumed by PV; latency hidden)
        short8 bv[8];
        #pragma unroll
        for (int n = 0; n < 8; ++n)
            bv[n] = *(const short8*)&Vt[(size_t)(16 * n + li) * S + kb + 8 * gl];

        // ---- QK^T swapped: D = S^T [key][q],  q = li (per-lane column)
        f32x4 sc[2][2];
        #pragma unroll
        for (int qs = 0; qs < 2; ++qs)
            #pragma unroll
            for (int kt = 0; kt < 2; ++kt)
                #pragma unroll
                for (int r = 0; r < 4; ++r) sc[qs][kt][r] = 0.f;
        __builtin_amdgcn_s_setprio(1);
        #pragma unroll
        for (int qs = 0; qs < 2; ++qs)
            #pragma unroll
            for (int kt = 0; kt < 2; ++kt)
                #pragma unroll
                for (int s = 0; s < 4; ++s)
                    sc[qs][kt] = __builtin_amdgcn_mfma_f32_16x16x32_bf16(
                        bkc[kt][s], aq[qs][s], sc[qs][kt], 0, 0, 0);
        __builtin_amdgcn_s_setprio(0);

        // ---- prefetch next iter's K (clamped)
        const int kn = (kb + 32 < kend) ? kb + 32 : kb;
        #pragma unroll
        for (int kt = 0; kt < 2; ++kt)
            #pragma unroll
            for (int s = 0; s < 4; ++s)
                bkn[kt][s] = *(const short8*)
                    &Kb[(size_t)(kn + 16 * kt + li) * DK + 32 * s + 8 * gl];

        // ---- scale + causal mask: key = kb+16kt+4gl+r, q = 32t+16qs+li
        #pragma unroll
        for (int qs = 0; qs < 2; ++qs) {
            const int q = 32 * t + 16 * qs + li;
            #pragma unroll
            for (int kt = 0; kt < 2; ++kt)
                #pragma unroll
                for (int r = 0; r < 4; ++r) {
                    const int key = kb + 16 * kt + 4 * gl + r;
                    sc[qs][kt][r] = (key > q) ? -1e30f : sc[qs][kt][r] * scale;
                }
        }

        // ---- per-q tile max: 7 in-lane fmax + 2 shfl (over gl groups)
        float tm[2];
        #pragma unroll
        for (int qs = 0; qs < 2; ++qs) {
            float v = fmaxf(fmaxf(fmaxf(sc[qs][0][0], sc[qs][0][1]),
                                  fmaxf(sc[qs][0][2], sc[qs][0][3])),
                            fmaxf(fmaxf(sc[qs][1][0], sc[qs][1][1]),
                                  fmaxf(sc[qs][1][2], sc[qs][1][3])));
            v = fmaxf(v, __shfl_xor(v, 16));
            v = fmaxf(v, __shfl_xor(v, 32));
            tm[qs] = v;
        }

        // ---- defer-max rescale (THR=6), wave-uniform branch
        const int need = (tm[0] > mr[0] + 6.f) | (tm[1] > mr[1] + 6.f);
        if (__any(need)) {
            float corr[2];
            #pragma unroll
            for (int qs = 0; qs < 2; ++qs) {
                const float mnew = fmaxf(mr[qs], tm[qs]);
                corr[qs] = __expf(mr[qs] - mnew);
                lr[qs] *= corr[qs];
                mr[qs]  = mnew;
            }
            #pragma unroll
            for (int qs = 0; qs < 2; ++qs)
                #pragma unroll
                for (int r = 0; r < 4; ++r) {
                    const float cr = __shfl(corr[qs], 4 * gl + r); // q=4gl+r
                    #pragma unroll
                    for (int n = 0; n < 8; ++n) accv[qs][n][r] *= cr;
                }
        }

        // ---- exp + row-sum (in-lane 8 + 2 shfl)
        #pragma unroll
        for (int qs = 0; qs < 2; ++qs) {
            float ps = 0.f;
            #pragma unroll
            for (int kt = 0; kt < 2; ++kt)
                #pragma unroll
                for (int r = 0; r < 4; ++r) {
                    const float p = __expf(sc[qs][kt][r] - mr[qs]);
                    sc[qs][kt][r] = p;
                    ps += p;
                }
            ps += __shfl_xor(ps, 16);
            ps += __shfl_xor(ps, 32);
            lr[qs] += ps;
        }

        // ---- P[q=li][k] -> LDS (packed 8B writes), reread as A-frag
        #pragma unroll
        for (int qs = 0; qs < 2; ++qs)
            #pragma unroll
            for (int kt = 0; kt < 2; ++kt) {
                u16x4 wv;
                #pragma unroll
                for (int r = 0; r < 4; ++r) wv[r] = f2bf(sc[qs][kt][r]);
                *(u16x4*)&Pl[16 * qs + li][16 * kt + 4 * gl] = wv;
            }
        // single-wave block: compiler's lgkmcnt ordering suffices (no barrier)
        const short8 pa0 = *(const short8*)&Pl[li][8 * gl];
        const short8 pa1 = *(const short8*)&Pl[16 + li][8 * gl];

        // ---- PV
        __builtin_amdgcn_s_setprio(1);
        #pragma unroll
        for (int n = 0; n < 8; ++n) {
            accv[0][n] = __builtin_amdgcn_mfma_f32_16x16x32_bf16(pa0, bv[n], accv[0][n], 0, 0, 0);
            accv[1][n] = __builtin_amdgcn_mfma_f32_16x16x32_bf16(pa1, bv[n], accv[1][n], 0, 0, 0);
        }
        __builtin_amdgcn_s_setprio(0);

        // ---- rotate K buffers
        #pragma unroll
        for (int kt = 0; kt < 2; ++kt)
            #pragma unroll
            for (int s = 0; s < 4; ++s) bkc[kt][s] = bkn[kt][s];
    }

    // ---- store unnormalized partial O + per-lane (m,l)
    #pragma unroll
    for (int qs = 0; qs < 2; ++qs)
        #pragma unroll
        for (int n = 0; n < 8; ++n)
            #pragma unroll
            for (int r = 0; r < 4; ++r)
                OP[((size_t)b * 32 + 16 * qs + 4 * gl + r) * DK + 16 * n + li]
                    = accv[qs][n][r];
    if (gl == 0) {
        #pragma unroll
        for (int qs = 0; qs < 2; ++qs) {
            ML[((size_t)b * 32 + 16 * qs + li) * 2 + 0] = mr[qs];
            ML[((size_t)b * 32 + 16 * qs + li) * 2 + 1] = lr[qs];
        }
    }
}

// ---------------------------------------------------------------------------
// Merge <=32 causal-split partials per q-row. grid = S blocks, block = DK.
// Tile t = row>>5 has j = (t>>2)+1 chunks, base = 2j(j-1) + (t&3)*j.
// ---------------------------------------------------------------------------
__global__ __launch_bounds__(DK) void merge_kernel(
    const float* __restrict__ OP, const float* __restrict__ ML,
    float* __restrict__ out)
{
    const int row = blockIdx.x, dv = threadIdx.x;
    const int t  = row >> 5, rl = row & 31;
    const int j  = (t >> 2) + 1;
    const int base = 2 * j * (j - 1) + (t & 3) * j;

    float M = -1e30f;
    for (int c = 0; c < j; ++c)
        M = fmaxf(M, ML[((size_t)(base + c) * 32 + rl) * 2]);
    float L = 0.f, o = 0.f;
    for (int c = 0; c < j; ++c) {
        const float mc = ML[((size_t)(base + c) * 32 + rl) * 2 + 0];
        const float lc = ML[((size_t)(base + c) * 32 + rl) * 2 + 1];
        const float wgt = __expf(mc - M);
        L += lc * wgt;
        o += wgt * OP[((size_t)(base + c) * 32 + rl) * DK + dv];
    }
    out[(size_t)row * DK + dv] = o / L;
}

// ---------------------------------------------------------------------------
extern "C" void kernel_launch(void* const* d_in, const int* in_sizes, int n_in,
                              void* d_out, int out_size, void* d_ws, size_t ws_size,
                              hipStream_t stream)
{
    (void)in_sizes; (void)n_in; (void)out_size; (void)ws_size;
    const float* X  = (const float*)d_in[0];
    const float* Wq = (const float*)d_in[1];
    const float* bq = (const float*)d_in[2];
    const float* Wk = (const float*)d_in[3];
    const float* bk = (const float*)d_in[4];
    const float* Wv = (const float*)d_in[5];
    const float* bv = (const float*)d_in[6];
    float* out = (float*)d_out;

    // ws (~39 MB): Wb | Qb | Kb | Vt | union{ Xb (dead after proj),
    //                                         OP [2112][32][DK] + ML }
    unsigned short* Wb = (unsigned short*)d_ws;
    unsigned short* Qb = Wb + (size_t)3 * DK * DMODEL;
    unsigned short* Kb = Qb + (size_t)S * DK;
    unsigned short* Vt = Kb + (size_t)S * DK;
    unsigned short* Xb = Vt + (size_t)S * DK;
    float* OP = (float*)Xb;                      // aliases Xb (sequential use)
    float* ML = OP + (size_t)NB_ATTN * 32 * DK;

    cvt_kernel<<<2240, 256, 0, stream>>>(X, Wq, Wk, Wv, Xb, Wb);
    proj_gemm<<<dim3(S / 16, 3), 128, 0, stream>>>(
        Xb, Wb, bq, bk, bv, Qb, Kb, Vt);
    attn_mfma<<<NB_ATTN, 64, 0, stream>>>(Qb, Kb, Vt, OP, ML);
    merge_kernel<<<S, DK, 0, stream>>>(OP, ML, out);
}

// Round 7
// 146.971 us; speedup vs baseline: 1.0360x; 1.0360x over previous
//
#include <hip/hip_runtime.h>
#include <hip/hip_bf16.h>

#define S 4096
#define DMODEL 1024
#define DK 128
#define NB_ATTN 528   // sum_{T=0}^{31} (T+1): 128-row q-tiles, 128-key chunks

typedef __attribute__((ext_vector_type(8))) short  short8;   // 8 x bf16 (4 VGPRs)
typedef __attribute__((ext_vector_type(4))) float  f32x4;    // MFMA accumulator
typedef __attribute__((ext_vector_type(4))) unsigned short u16x4;  // 8B pack

__device__ __forceinline__ unsigned short f2bf(float f) {
    return __builtin_bit_cast(unsigned short, __float2bfloat16(f));
}

__device__ __forceinline__ short8 cvt8(float4 a, float4 b) {
    short8 v;
    v[0] = (short)f2bf(a.x); v[1] = (short)f2bf(a.y);
    v[2] = (short)f2bf(a.z); v[3] = (short)f2bf(a.w);
    v[4] = (short)f2bf(b.x); v[5] = (short)f2bf(b.y);
    v[6] = (short)f2bf(b.z); v[7] = (short)f2bf(b.w);
    return v;
}

// ---------------------------------------------------------------------------
// Convert X [S][DMODEL] f32 -> Xb bf16; Wq|Wk|Wv [DK][DMODEL] f32 -> Wb bf16.
// ---------------------------------------------------------------------------
__global__ __launch_bounds__(256) void cvt_kernel(
    const float* __restrict__ X,
    const float* __restrict__ Wq, const float* __restrict__ Wk,
    const float* __restrict__ Wv,
    unsigned short* __restrict__ Xb, unsigned short* __restrict__ Wb)
{
    const int i = blockIdx.x * 256 + threadIdx.x;
    const float* __restrict__ src;
    unsigned short* __restrict__ dst;
    size_t off;
    if (i < 524288) {
        src = X; dst = Xb; off = (size_t)i * 8;
    } else {
        const int j   = i - 524288;
        const int sel = j >> 14, jj = j & 16383;
        src = sel == 0 ? Wq : sel == 1 ? Wk : Wv;
        dst = Wb + (size_t)sel * DK * DMODEL;
        off = (size_t)jj * 8;
    }
    const float4 a = *(const float4*)(src + off);
    const float4 b = *(const float4*)(src + off + 4);
    *(short8*)(dst + off) = cvt8(a, b);
}

// ---------------------------------------------------------------------------
// QKV projection GEMM, bf16. grid = (S/16, 3, 2), block = 128 (2 waves).
// Wave: 16 rows x 32 cols (2 MFMA tiles); 3072 waves = 3/SIMD for latency
// hiding. sel==2 (V) writes DIRECTLY TRANSPOSED to Vt[DK][S] (8B stores).
// ---------------------------------------------------------------------------
__global__ __launch_bounds__(128) void proj_gemm(
    const unsigned short* __restrict__ Xb, const unsigned short* __restrict__ Wb,
    const float* __restrict__ bq, const float* __restrict__ bk,
    const float* __restrict__ bv,
    unsigned short* __restrict__ Qb, unsigned short* __restrict__ Kb,
    unsigned short* __restrict__ Vt)
{
    const int sel = blockIdx.y;
    const float* __restrict__ bias = sel == 0 ? bq : sel == 1 ? bk : bv;
    const unsigned short* __restrict__ wbase = Wb + (size_t)sel * DK * DMODEL;

    const int tid = threadIdx.x, w = tid >> 6, lane = tid & 63;
    const int li = lane & 15, gl = lane >> 4;
    const int r0 = blockIdx.x * 16;
    const int n0 = blockIdx.z * 64 + w * 32;

    f32x4 acc[2];
    #pragma unroll
    for (int j = 0; j < 2; ++j)
        #pragma unroll
        for (int r = 0; r < 4; ++r) acc[j][r] = 0.f;

    const unsigned short* ap  = &Xb[(size_t)(r0 + li) * DMODEL + 8 * gl];
    const unsigned short* bp0 = &wbase[(size_t)(n0 + li) * DMODEL + 8 * gl];
    const unsigned short* bp1 = bp0 + (size_t)16 * DMODEL;

    #pragma unroll 4
    for (int k0 = 0; k0 < DMODEL; k0 += 32) {
        const short8 a  = *(const short8*)(ap + k0);
        const short8 b0 = *(const short8*)(bp0 + k0);
        const short8 b1 = *(const short8*)(bp1 + k0);
        acc[0] = __builtin_amdgcn_mfma_f32_16x16x32_bf16(a, b0, acc[0], 0, 0, 0);
        acc[1] = __builtin_amdgcn_mfma_f32_16x16x32_bf16(a, b1, acc[1], 0, 0, 0);
    }

    if (sel < 2) {
        unsigned short* __restrict__ Out = sel == 0 ? Qb : Kb;
        #pragma unroll
        for (int j = 0; j < 2; ++j)
            #pragma unroll
            for (int r = 0; r < 4; ++r) {
                const int row = r0 + 4 * gl + r;
                const int col = n0 + 16 * j + li;
                Out[(size_t)row * DK + col] = f2bf(acc[j][r] + bias[col]);
            }
    } else {
        #pragma unroll
        for (int j = 0; j < 2; ++j) {
            const int col = n0 + 16 * j + li;          // dv
            const float bb = bias[col];
            u16x4 wv;
            #pragma unroll
            for (int r = 0; r < 4; ++r) wv[r] = f2bf(acc[j][r] + bb);
            *(u16x4*)&Vt[(size_t)col * S + r0 + 4 * gl] = wv;  // rows 4gl..4gl+3
        }
    }
}

// ---------------------------------------------------------------------------
// Flash attention, bf16 MFMA, swapped QK^T, 4-wave blocks with LDS-shared
// K/V tiles. Block = 256 thr = 4 waves; owns 128 q-rows (wave w: rows
// 128T+32w..+31) x one 128-key chunk -> 528 UNIFORM blocks of exactly 4
// 32-key iters (2.06 blocks/CU, all co-resident). Per iter: K tile 32x128
// + V tile 128x32 staged to LDS (T14: issue loads early, ds_write after
// compute, one barrier) shared by 4 waves -> 4x less L2 read traffic.
// Inner math identical to verified round-6 kernel (frag layouts, swapped
// softmax, Pl bounce, PV). Partials written nontemporal (L2 thrash fix).
// ---------------------------------------------------------------------------
__global__ __launch_bounds__(256, 2) void attn_mfma(
    const unsigned short* __restrict__ Qb,
    const unsigned short* __restrict__ Kb,
    const unsigned short* __restrict__ Vt,
    float* __restrict__ OP, float* __restrict__ ML)
{
    const int bb = blockIdx.x;
    int T = 0;
    while ((T + 1) * (T + 2) / 2 <= bb) ++T;         // <=31 scalar iters
    const int c = bb - T * (T + 1) / 2;
    const int kstart = 128 * c;                      // always 4 full iters

    const int tid = threadIdx.x, w = tid >> 6, lane = tid & 63;
    const int li = lane & 15, gl = lane >> 4;
    const int q0 = 128 * T + 32 * w;

    __shared__ unsigned short Ks[2][32 * DK];   // [key][dk]   8 KB each
    __shared__ unsigned short Vs[2][DK * 32];   // [dv][key]   8 KB each
    __shared__ unsigned short Pl[4][32][40];    // per-wave P bounce

    // ---- Q fragments (A-layout rows = q)
    short8 aq[2][4];
    #pragma unroll
    for (int qs = 0; qs < 2; ++qs)
        #pragma unroll
        for (int s = 0; s < 4; ++s)
            aq[qs][s] = *(const short8*)
                &Qb[(size_t)(q0 + 16 * qs + li) * DK + 32 * s + 8 * gl];

    f32x4 accv[2][8];
    #pragma unroll
    for (int qs = 0; qs < 2; ++qs)
        #pragma unroll
        for (int n = 0; n < 8; ++n)
            #pragma unroll
            for (int r = 0; r < 4; ++r) accv[qs][n][r] = 0.f;

    float mr[2] = {-1e30f, -1e30f}, lr[2] = {0.f, 0.f};
    const float scale = 0.08838834764831845f;  // 1/sqrt(128)

    // ---- staging maps (16B chunks, 256 threads, 8KB per tile):
    // K: chunk ch in {tid, tid+256}: key = ch>>4, col8 = ch&15
    // V: chunk ch in {tid, tid+256}: dv  = ch>>2, part  = ch&3
    // prologue: stage buf 0 for kstart
    {
        short8 st0 = *(const short8*)&Kb[(size_t)(kstart + (tid >> 4)) * DK + (tid & 15) * 8];
        short8 st1 = *(const short8*)&Kb[(size_t)(kstart + (tid >> 4) + 16) * DK + (tid & 15) * 8];
        short8 st2 = *(const short8*)&Vt[(size_t)(tid >> 2) * S + kstart + (tid & 3) * 8];
        short8 st3 = *(const short8*)&Vt[(size_t)((tid >> 2) + 64) * S + kstart + (tid & 3) * 8];
        *(short8*)&Ks[0][(size_t)tid * 8]         = st0;
        *(short8*)&Ks[0][(size_t)(tid + 256) * 8] = st1;
        *(short8*)&Vs[0][(size_t)tid * 8]         = st2;
        *(short8*)&Vs[0][(size_t)(tid + 256) * 8] = st3;
    }
    __syncthreads();

    int cur = 0;
    for (int it = 0; it < 4; ++it) {
        const int kb = kstart + 32 * it;
        const bool pf = (it < 3);

        // ---- issue next tile's global loads NOW (land during compute)
        short8 st0, st1, st2, st3;
        if (pf) {
            const int kn = kb + 32;
            st0 = *(const short8*)&Kb[(size_t)(kn + (tid >> 4)) * DK + (tid & 15) * 8];
            st1 = *(const short8*)&Kb[(size_t)(kn + (tid >> 4) + 16) * DK + (tid & 15) * 8];
            st2 = *(const short8*)&Vt[(size_t)(tid >> 2) * S + kn + (tid & 3) * 8];
            st3 = *(const short8*)&Vt[(size_t)((tid >> 2) + 64) * S + kn + (tid & 3) * 8];
        }

        // ---- K/V fragments from LDS
        const unsigned short* Ksb = &Ks[cur][0];
        const unsigned short* Vsb = &Vs[cur][0];
        short8 kf[2][4], vf[8];
        #pragma unroll
        for (int kt = 0; kt < 2; ++kt)
            #pragma unroll
            for (int s = 0; s < 4; ++s)
                kf[kt][s] = *(const short8*)&Ksb[(16 * kt + li) * DK + 32 * s + 8 * gl];
        #pragma unroll
        for (int n = 0; n < 8; ++n)
            vf[n] = *(const short8*)&Vsb[(16 * n + li) * 32 + 8 * gl];

        // ---- QK^T swapped: D = S^T [key][q], q = li (per-lane column)
        f32x4 sc[2][2];
        #pragma unroll
        for (int qs = 0; qs < 2; ++qs)
            #pragma unroll
            for (int kt = 0; kt < 2; ++kt)
                #pragma unroll
                for (int r = 0; r < 4; ++r) sc[qs][kt][r] = 0.f;
        __builtin_amdgcn_s_setprio(1);
        #pragma unroll
        for (int qs = 0; qs < 2; ++qs)
            #pragma unroll
            for (int kt = 0; kt < 2; ++kt)
                #pragma unroll
                for (int s = 0; s < 4; ++s)
                    sc[qs][kt] = __builtin_amdgcn_mfma_f32_16x16x32_bf16(
                        kf[kt][s], aq[qs][s], sc[qs][kt], 0, 0, 0);
        __builtin_amdgcn_s_setprio(0);

        // ---- scale + causal mask: key = kb+16kt+4gl+r, q = q0+16qs+li
        #pragma unroll
        for (int qs = 0; qs < 2; ++qs) {
            const int q = q0 + 16 * qs + li;
            #pragma unroll
            for (int kt = 0; kt < 2; ++kt)
                #pragma unroll
                for (int r = 0; r < 4; ++r) {
                    const int key = kb + 16 * kt + 4 * gl + r;
                    sc[qs][kt][r] = (key > q) ? -1e30f : sc[qs][kt][r] * scale;
                }
        }

        // ---- per-q tile max: 7 in-lane fmax + 2 shfl
        float tm[2];
        #pragma unroll
        for (int qs = 0; qs < 2; ++qs) {
            float v = fmaxf(fmaxf(fmaxf(sc[qs][0][0], sc[qs][0][1]),
                                  fmaxf(sc[qs][0][2], sc[qs][0][3])),
                            fmaxf(fmaxf(sc[qs][1][0], sc[qs][1][1]),
                                  fmaxf(sc[qs][1][2], sc[qs][1][3])));
            v = fmaxf(v, __shfl_xor(v, 16));
            v = fmaxf(v, __shfl_xor(v, 32));
            tm[qs] = v;
        }

        // ---- defer-max rescale (THR=6), wave-uniform branch
        const int need = (tm[0] > mr[0] + 6.f) | (tm[1] > mr[1] + 6.f);
        if (__any(need)) {
            float corr[2];
            #pragma unroll
            for (int qs = 0; qs < 2; ++qs) {
                const float mnew = fmaxf(mr[qs], tm[qs]);
                corr[qs] = __expf(mr[qs] - mnew);
                lr[qs] *= corr[qs];
                mr[qs]  = mnew;
            }
            #pragma unroll
            for (int qs = 0; qs < 2; ++qs)
                #pragma unroll
                for (int r = 0; r < 4; ++r) {
                    const float cr = __shfl(corr[qs], 4 * gl + r); // q=4gl+r
                    #pragma unroll
                    for (int n = 0; n < 8; ++n) accv[qs][n][r] *= cr;
                }
        }

        // ---- exp + row-sum (in-lane 8 + 2 shfl)
        #pragma unroll
        for (int qs = 0; qs < 2; ++qs) {
            float ps = 0.f;
            #pragma unroll
            for (int kt = 0; kt < 2; ++kt)
                #pragma unroll
                for (int r = 0; r < 4; ++r) {
                    const float p = __expf(sc[qs][kt][r] - mr[qs]);
                    sc[qs][kt][r] = p;
                    ps += p;
                }
            ps += __shfl_xor(ps, 16);
            ps += __shfl_xor(ps, 32);
            lr[qs] += ps;
        }

        // ---- P[q=li][k] -> per-wave LDS (8B packs), reread as A-frag
        #pragma unroll
        for (int qs = 0; qs < 2; ++qs)
            #pragma unroll
            for (int kt = 0; kt < 2; ++kt) {
                u16x4 wv;
                #pragma unroll
                for (int r = 0; r < 4; ++r) wv[r] = f2bf(sc[qs][kt][r]);
                *(u16x4*)&Pl[w][16 * qs + li][16 * kt + 4 * gl] = wv;
            }
        const short8 pa0 = *(const short8*)&Pl[w][li][8 * gl];
        const short8 pa1 = *(const short8*)&Pl[w][16 + li][8 * gl];

        // ---- PV
        __builtin_amdgcn_s_setprio(1);
        #pragma unroll
        for (int n = 0; n < 8; ++n) {
            accv[0][n] = __builtin_amdgcn_mfma_f32_16x16x32_bf16(pa0, vf[n], accv[0][n], 0, 0, 0);
            accv[1][n] = __builtin_amdgcn_mfma_f32_16x16x32_bf16(pa1, vf[n], accv[1][n], 0, 0, 0);
        }
        __builtin_amdgcn_s_setprio(0);

        // ---- write next tile to LDS, barrier (drains vm+lgkm), swap
        if (pf) {
            *(short8*)&Ks[cur ^ 1][(size_t)tid * 8]         = st0;
            *(short8*)&Ks[cur ^ 1][(size_t)(tid + 256) * 8] = st1;
            *(short8*)&Vs[cur ^ 1][(size_t)tid * 8]         = st2;
            *(short8*)&Vs[cur ^ 1][(size_t)(tid + 256) * 8] = st3;
            __syncthreads();
        }
        cur ^= 1;
    }

    // ---- store unnormalized partial O + per-lane (m,l), nontemporal
    #pragma unroll
    for (int qs = 0; qs < 2; ++qs)
        #pragma unroll
        for (int n = 0; n < 8; ++n)
            #pragma unroll
            for (int r = 0; r < 4; ++r)
                __builtin_nontemporal_store(accv[qs][n][r],
                    &OP[((size_t)bb * 128 + 32 * w + 16 * qs + 4 * gl + r) * DK
                        + 16 * n + li]);
    if (gl == 0) {
        #pragma unroll
        for (int qs = 0; qs < 2; ++qs) {
            ML[((size_t)bb * 128 + 32 * w + 16 * qs + li) * 2 + 0] = mr[qs];
            ML[((size_t)bb * 128 + 32 * w + 16 * qs + li) * 2 + 1] = lr[qs];
        }
    }
}

// ---------------------------------------------------------------------------
// Merge <=32 causal-split partials per q-row. grid = S blocks, block = DK.
// Row's tile T = row>>7 has j = T+1 chunks at base = T(T+1)/2.
// ---------------------------------------------------------------------------
__global__ __launch_bounds__(DK) void merge_kernel(
    const float* __restrict__ OP, const float* __restrict__ ML,
    float* __restrict__ out)
{
    const int row = blockIdx.x, dv = threadIdx.x;
    const int T  = row >> 7, rl = row & 127;
    const int j  = T + 1;
    const int base = T * (T + 1) / 2;

    float M = -1e30f;
    for (int c = 0; c < j; ++c)
        M = fmaxf(M, ML[((size_t)(base + c) * 128 + rl) * 2]);
    float L = 0.f, o = 0.f;
    #pragma unroll 2
    for (int c = 0; c < j; ++c) {
        const float mc = ML[((size_t)(base + c) * 128 + rl) * 2 + 0];
        const float lc = ML[((size_t)(base + c) * 128 + rl) * 2 + 1];
        const float wgt = __expf(mc - M);
        L += lc * wgt;
        o += wgt * __builtin_nontemporal_load(
                 &OP[((size_t)(base + c) * 128 + rl) * DK + dv]);
    }
    out[(size_t)row * DK + dv] = o / L;
}

// ---------------------------------------------------------------------------
extern "C" void kernel_launch(void* const* d_in, const int* in_sizes, int n_in,
                              void* d_out, int out_size, void* d_ws, size_t ws_size,
                              hipStream_t stream)
{
    (void)in_sizes; (void)n_in; (void)out_size; (void)ws_size;
    const float* X  = (const float*)d_in[0];
    const float* Wq = (const float*)d_in[1];
    const float* bq = (const float*)d_in[2];
    const float* Wk = (const float*)d_in[3];
    const float* bk = (const float*)d_in[4];
    const float* Wv = (const float*)d_in[5];
    const float* bv = (const float*)d_in[6];
    float* out = (float*)d_out;

    // ws (~39 MB): Wb | Qb | Kb | Vt | union{ Xb (dead after proj),
    //                                         OP [528][128][DK] f32 + ML }
    unsigned short* Wb = (unsigned short*)d_ws;
    unsigned short* Qb = Wb + (size_t)3 * DK * DMODEL;
    unsigned short* Kb = Qb + (size_t)S * DK;
    unsigned short* Vt = Kb + (size_t)S * DK;
    unsigned short* Xb = Vt + (size_t)S * DK;
    float* OP = (float*)Xb;                      // aliases Xb (sequential use)
    float* ML = OP + (size_t)NB_ATTN * 128 * DK;

    cvt_kernel<<<2240, 256, 0, stream>>>(X, Wq, Wk, Wv, Xb, Wb);
    proj_gemm<<<dim3(S / 16, 3, 2), 128, 0, stream>>>(
        Xb, Wb, bq, bk, bv, Qb, Kb, Vt);
    attn_mfma<<<NB_ATTN, 256, 0, stream>>>(Qb, Kb, Vt, OP, ML);
    merge_kernel<<<S, DK, 0, stream>>>(OP, ML, out);
}